// Round 1
// baseline (5274.379 us; speedup 1.0000x reference)
//
#include <hip/hip_runtime.h>
#include <cmath>

#define HIDDEN   256
#define NLAYERS  4
#define NPTS     131072
#define PPW      16            // points per workgroup
#define KT       32            // k-tile rows of W staged in LDS
#define SSTRIDE  100           // dwords per k-row of state (6*16=96 + 4 pad, mult of 4)
#define NWG      (NPTS / PPW)  // 8192

__device__ __forceinline__ float f4get(const float4& v, int i) {
    switch (i) { case 0: return v.x; case 1: return v.y; case 2: return v.z; default: return v.w; }
}

// State layout in LDS: S[k][s][p] at dword offset k*SSTRIDE + s*16 + p
//   k = hidden element (0..255), s = state id (0:h 1:g0 2:g1 3:gt 4:s0 5:s1), p = point (0..15)
// Thread (tj,tp): tj=tid>>2 owns j in [4tj,4tj+4), tp=tid&3 owns p in [4tp,4tp+4)
__global__ __launch_bounds__(256, 1)
void pinn_fused_kernel(const float* __restrict__ X,
                       const float* __restrict__ W_in, const float* __restrict__ b_in,
                       const float* __restrict__ W_h,  const float* __restrict__ b_h,
                       const float* __restrict__ W_out,
                       double* __restrict__ partials)
{
    extern __shared__ float lds[];
    float* S    = lds;                        // HIDDEN * SSTRIDE floats (100 KB)
    float* Wlds = lds + HIDDEN * SSTRIDE;     // KT * HIDDEN floats (32 KB)

    const int tid   = threadIdx.x;
    const int tj    = tid >> 2;
    const int tp    = tid & 3;
    const int jbase = tj * 4;
    const int pbase = tp * 4;
    const int wg    = blockIdx.x;
    const int pt0   = wg * PPW;

    // ---------------- input layer: x(3) -> h(256), jets in registers ----------------
    {
        float4 w0 = *(const float4*)(W_in + 0 * HIDDEN + jbase);
        float4 w1 = *(const float4*)(W_in + 1 * HIDDEN + jbase);
        float4 w2 = *(const float4*)(W_in + 2 * HIDDEN + jbase);
        float4 bi = *(const float4*)(b_in + jbase);

        float xv[4][3];
#pragma unroll
        for (int pp = 0; pp < 4; ++pp) {
            const float* xp = X + (size_t)(pt0 + pbase + pp) * 3;
            xv[pp][0] = xp[0]; xv[pp][1] = xp[1]; xv[pp][2] = xp[2];
        }
#pragma unroll
        for (int jj = 0; jj < 4; ++jj) {
            float wj0 = f4get(w0, jj), wj1 = f4get(w1, jj), wj2 = f4get(w2, jj), bj = f4get(bi, jj);
            float o[6][4];
#pragma unroll
            for (int pp = 0; pp < 4; ++pp) {
                float z  = fmaf(xv[pp][0], wj0, fmaf(xv[pp][1], wj1, fmaf(xv[pp][2], wj2, bj)));
                float a  = tanhf(z);
                float td = 1.f - a * a;        // tanh'
                float m2 = -2.f * a * td;      // tanh''
                o[0][pp] = a;
                o[1][pp] = td * wj0;           // dv/dx0 jet
                o[2][pp] = td * wj1;           // dv/dx1 jet
                o[3][pp] = td * wj2;           // dv/dt jet
                o[4][pp] = m2 * wj0 * wj0;     // d2v/dx0^2 jet (z''=0)
                o[5][pp] = m2 * wj1 * wj1;     // d2v/dx1^2 jet
            }
            int j = jbase + jj;
#pragma unroll
            for (int s = 0; s < 6; ++s)
                *(float4*)&S[j * SSTRIDE + s * 16 + pbase] =
                    make_float4(o[s][0], o[s][1], o[s][2], o[s][3]);
        }
    }

    // ---------------- hidden layers: 6-state batched matvec + tanh chain ----------------
    for (int l = 0; l < NLAYERS; ++l) {
        const float* Wl = W_h + (size_t)l * HIDDEN * HIDDEN;
        float4 bl = *(const float4*)(b_h + l * HIDDEN + jbase);

        float acc[6][4][4];
#pragma unroll
        for (int jj = 0; jj < 4; ++jj)
#pragma unroll
            for (int pp = 0; pp < 4; ++pp) {
                acc[0][jj][pp] = f4get(bl, jj);
                acc[1][jj][pp] = 0.f; acc[2][jj][pp] = 0.f; acc[3][jj][pp] = 0.f;
                acc[4][jj][pp] = 0.f; acc[5][jj][pp] = 0.f;
            }

        for (int kt_ = 0; kt_ < HIDDEN / KT; ++kt_) {
            __syncthreads();   // prev tile reads done / state writes visible
            // stage W[kt_*KT .. +KT)[0..256) into LDS, coalesced float4
            {
                const float4* src4 = (const float4*)(Wl + (size_t)kt_ * KT * HIDDEN);
                float4*       dst4 = (float4*)Wlds;
#pragma unroll
                for (int i = 0; i < (KT * HIDDEN / 4) / 256; ++i)
                    dst4[tid + i * 256] = src4[tid + i * 256];
            }
            __syncthreads();   // tile visible

#pragma unroll 4
            for (int kk = 0; kk < KT; ++kk) {
                const int k = kt_ * KT + kk;
                float4 wf = *(const float4*)&Wlds[kk * HIDDEN + jbase];
                float4 sf[6];
#pragma unroll
                for (int s = 0; s < 6; ++s)
                    sf[s] = *(const float4*)&S[k * SSTRIDE + s * 16 + pbase];
#pragma unroll
                for (int s = 0; s < 6; ++s)
#pragma unroll
                    for (int jj = 0; jj < 4; ++jj)
#pragma unroll
                        for (int pp = 0; pp < 4; ++pp)
                            acc[s][jj][pp] = fmaf(f4get(wf, jj), f4get(sf[s], pp), acc[s][jj][pp]);
            }
        }

        __syncthreads();   // all waves done reading S this layer
        // elementwise tanh jet chain, write back to S in place
#pragma unroll
        for (int jj = 0; jj < 4; ++jj) {
            float o[6][4];
#pragma unroll
            for (int pp = 0; pp < 4; ++pp) {
                float z   = acc[0][jj][pp];
                float a   = tanhf(z);
                float td  = 1.f - a * a;
                float m2  = -2.f * a * td;
                float zg0 = acc[1][jj][pp], zg1 = acc[2][jj][pp], zt = acc[3][jj][pp];
                float zs0 = acc[4][jj][pp], zs1 = acc[5][jj][pp];
                o[0][pp] = a;
                o[1][pp] = td * zg0;
                o[2][pp] = td * zg1;
                o[3][pp] = td * zt;
                o[4][pp] = fmaf(m2 * zg0, zg0, td * zs0);   // t''*(z')^2 + t'*z''
                o[5][pp] = fmaf(m2 * zg1, zg1, td * zs1);
            }
            int j = jbase + jj;
#pragma unroll
            for (int s = 0; s < 6; ++s)
                *(float4*)&S[j * SSTRIDE + s * 16 + pbase] =
                    make_float4(o[s][0], o[s][1], o[s][2], o[s][3]);
        }
    }

    __syncthreads();   // final state visible

    // ---------------- output layer: residual = W_out . (gt - s0 - s1) ----------------
    float4 wo = *(const float4*)(W_out + jbase);
    float part[4] = {0.f, 0.f, 0.f, 0.f};
#pragma unroll
    for (int jj = 0; jj < 4; ++jj) {
        int j = jbase + jj;
        float4 gt4 = *(const float4*)&S[j * SSTRIDE + 3 * 16 + pbase];
        float4 s04 = *(const float4*)&S[j * SSTRIDE + 4 * 16 + pbase];
        float4 s14 = *(const float4*)&S[j * SSTRIDE + 5 * 16 + pbase];
        float wj = f4get(wo, jj);
#pragma unroll
        for (int pp = 0; pp < 4; ++pp)
            part[pp] = fmaf(wj, f4get(gt4, pp) - f4get(s04, pp) - f4get(s14, pp), part[pp]);
    }

    // deterministic in-workgroup reduction (reuse Wlds area)
    float* red = Wlds;                    // [64][16]
#pragma unroll
    for (int pp = 0; pp < 4; ++pp) red[tj * 16 + pbase + pp] = part[pp];
    __syncthreads();

    double* sq = (double*)(Wlds + 1024);  // 16 doubles
    if (tid < PPW) {
        double ssum = 0.0;
        for (int t = 0; t < 64; ++t) ssum += (double)red[t * 16 + tid];  // fixed order
        sq[tid] = ssum * ssum;
    }
    __syncthreads();
    if (tid == 0) {
        double tot = 0.0;
        for (int p = 0; p < PPW; ++p) tot += sq[p];                      // fixed order
        partials[wg] = tot;
    }
}

__global__ void pinn_reduce_kernel(const double* __restrict__ partials, float* __restrict__ out)
{
    __shared__ double sh[256];
    double t = 0.0;
    for (int i = 0; i < NWG / 256; ++i) t += partials[threadIdx.x * (NWG / 256) + i]; // fixed order
    sh[threadIdx.x] = t;
    __syncthreads();
    for (int ofs = 128; ofs > 0; ofs >>= 1) {
        if ((int)threadIdx.x < ofs) sh[threadIdx.x] += sh[threadIdx.x + ofs];
        __syncthreads();
    }
    if (threadIdx.x == 0) {
        out[0] = (float)(sh[0] / (double)NPTS);  // pde_loss
        out[1] = 0.f;                            // ode_loss
    }
}

extern "C" void kernel_launch(void* const* d_in, const int* in_sizes, int n_in,
                              void* d_out, int out_size, void* d_ws, size_t ws_size,
                              hipStream_t stream)
{
    const float* X     = (const float*)d_in[0];
    const float* W_in  = (const float*)d_in[1];
    const float* b_in  = (const float*)d_in[2];
    const float* W_h   = (const float*)d_in[3];
    const float* b_h   = (const float*)d_in[4];
    const float* W_out = (const float*)d_in[5];
    // d_in[6] = b_out, unused (constant offset has zero derivative)

    double* partials = (double*)d_ws;
    float*  out      = (float*)d_out;

    const size_t lds_bytes = (size_t)(HIDDEN * SSTRIDE + KT * HIDDEN) * sizeof(float); // 132 KB
    (void)hipFuncSetAttribute((const void*)pinn_fused_kernel,
                              hipFuncAttributeMaxDynamicSharedMemorySize, (int)lds_bytes);

    hipLaunchKernelGGL(pinn_fused_kernel, dim3(NWG), dim3(256), lds_bytes, stream,
                       X, W_in, b_in, W_h, b_h, W_out, partials);
    hipLaunchKernelGGL(pinn_reduce_kernel, dim3(1), dim3(256), 0, stream,
                       partials, out);
}

// Round 2
// 1533.785 us; speedup vs baseline: 3.4388x; 3.4388x over previous
//
#include <hip/hip_runtime.h>

typedef __attribute__((ext_vector_type(8))) short  short8;
typedef __attribute__((ext_vector_type(4))) float  f32x4;

#define HIDDEN   256
#define NLAYERS  4
#define NPTS     131072
#define PPW      16
#define NWG      (NPTS / PPW)          // 8192

// workspace layout (bytes)
#define WS_PARTIALS   0                          // 8192 doubles = 64 KB
#define WS_WHI        65536
#define WPLANE_BYTES  (4 * 16 * 8 * 1024)        // 4 layers x 16 jt x 8 kt x 1KB = 512 KB
#define WS_WLO        (WS_WHI + WPLANE_BYTES)    // total ws use: 64KB + 1MB

__device__ __forceinline__ unsigned short f2bf(float f) {
    unsigned u = __float_as_uint(f);
    u += 0x7FFFu + ((u >> 16) & 1u);             // round-to-nearest-even
    return (unsigned short)(u >> 16);
}
__device__ __forceinline__ float bf2f(unsigned short h) {
    return __uint_as_float(((unsigned)h) << 16);
}
__device__ __forceinline__ float fast_tanh(float z) {
    float az = fabsf(z);
    float e  = __expf(2.f * az);                 // inf for big az -> r = 1, no NaN
    float r  = 1.f - __fdividef(2.f, e + 1.f);
    return copysignf(r, z);
}

// ---------------- weight prep: split W_h into bf16 hi/lo, fragment-contiguous ----------------
// B-fragment (layer, jt, kt): lane l holds W[k][j] for j = jt*16 + (l&15),
// k = kt*32 + (l>>4)*8 + e  (e = 0..7), stored at frag_base + l*8 ushorts.
__global__ void prep_w(const float* __restrict__ Wh,
                       unsigned short* __restrict__ whi, unsigned short* __restrict__ wlo)
{
    int b    = blockIdx.x;               // 512 = 4 layers x 16 jt x 8 kt
    int lay  = b >> 7;
    int jt   = (b >> 3) & 15;
    int kt   = b & 7;
    int lane = threadIdx.x;              // 64
    int j    = jt * 16 + (lane & 15);
    int k0   = kt * 32 + (lane >> 4) * 8;
    const float* W = Wh + (size_t)lay * HIDDEN * HIDDEN;
    size_t base = ((size_t)(lay * 16 + jt) * 8 + kt) * 512 + (size_t)lane * 8;  // ushort units
#pragma unroll
    for (int e = 0; e < 8; ++e) {
        float w = W[(size_t)(k0 + e) * HIDDEN + j];
        unsigned short h = f2bf(w);
        whi[base + e] = h;
        wlo[base + e] = f2bf(w - bf2f(h));
    }
}

// ---------------- fused PINN kernel ----------------
// LDS state: 48 fragments per plane (mt = state 0..5, kt = 0..7), each 1 KB:
//   addr(plane, mt, kt, lane, e) = plane + (mt*8+kt)*1024 + lane*16 + e*2
// semantic: value(state s, point p, hidden j) at frag (s, j>>5),
//   lane = ((j>>3)&3)*16 + p, e = j&7.
__global__ __launch_bounds__(256, 1)
void pinn_mfma(const float* __restrict__ X,
               const float* __restrict__ W_in, const float* __restrict__ b_in,
               const float* __restrict__ b_h,  const float* __restrict__ W_out,
               const unsigned short* __restrict__ whi, const unsigned short* __restrict__ wlo,
               double* __restrict__ partials)
{
    extern __shared__ char lds[];
    char*   SH  = lds;                         // 48 KB  hi plane
    char*   SL  = lds + 48 * 1024;             // 48 KB  lo plane
    float*  xs  = (float*)(lds + 98304);       // 48 floats (pad to 256B)
    float*  red = (float*)(lds + 98304 + 256); // 256 floats
    double* sq  = (double*)(lds + 98304 + 256 + 1024); // 16 doubles

    const int tid  = threadIdx.x;
    const int lane = tid & 63;
    const int wid  = tid >> 6;
    const int wg   = blockIdx.x;
    const int pt0  = wg * PPW;

    if (tid < 48) xs[tid] = X[(size_t)pt0 * 3 + tid];
    __syncthreads();

    // ---- input layer: thread t owns hidden unit j = t; jets for 16 points ----
    {
        const int j  = tid;
        const int kt = j >> 5, kg = (j >> 3) & 3, e = j & 7;
        float w0 = W_in[j], w1 = W_in[HIDDEN + j], w2 = W_in[2 * HIDDEN + j], bj = b_in[j];
#pragma unroll
        for (int p = 0; p < PPW; ++p) {
            float x0 = xs[p * 3], x1 = xs[p * 3 + 1], x2 = xs[p * 3 + 2];
            float z  = fmaf(x0, w0, fmaf(x1, w1, fmaf(x2, w2, bj)));
            float a  = fast_tanh(z);
            float td = 1.f - a * a;
            float m2 = -2.f * a * td;
            float o[6] = { a, td * w0, td * w1, td * w2, m2 * w0 * w0, m2 * w1 * w1 };
#pragma unroll
            for (int s = 0; s < 6; ++s) {
                size_t off = (size_t)(s * 8 + kt) * 1024 + (size_t)(kg * 16 + p) * 16 + e * 2;
                unsigned short h = f2bf(o[s]);
                *(unsigned short*)(SH + off) = h;
                *(unsigned short*)(SL + off) = f2bf(o[s] - bf2f(h));
            }
        }
    }
    __syncthreads();

    // ---- hidden layers: split-bf16 MFMA GEMM (D[m][j] = sum_k S[m][k] * W[k][j]) ----
#pragma unroll 1
    for (int l = 0; l < NLAYERS; ++l) {
        float bias[4];
#pragma unroll
        for (int jj = 0; jj < 4; ++jj)
            bias[jj] = b_h[l * HIDDEN + (wid * 4 + jj) * 16 + (lane & 15)];

        f32x4 acc[4][6];
#pragma unroll
        for (int jj = 0; jj < 4; ++jj)
#pragma unroll
            for (int mt = 0; mt < 6; ++mt)
                acc[jj][mt] = (f32x4){0.f, 0.f, 0.f, 0.f};

#pragma unroll 2
        for (int kt = 0; kt < 8; ++kt) {
            short8 ah[6], al[6];
#pragma unroll
            for (int mt = 0; mt < 6; ++mt) {
                size_t fo = (size_t)(mt * 8 + kt) * 1024 + (size_t)lane * 16;
                ah[mt] = *(const short8*)(SH + fo);
                al[mt] = *(const short8*)(SL + fo);
            }
            short8 bh[4], bl[4];
#pragma unroll
            for (int jj = 0; jj < 4; ++jj) {
                size_t fo = ((size_t)(l * 16 + wid * 4 + jj) * 8 + kt) * 512 + (size_t)lane * 8;
                bh[jj] = *(const short8*)(whi + fo);
                bl[jj] = *(const short8*)(wlo + fo);
            }
            // 4 split products, product-major for acc dependency distance
#pragma unroll
            for (int jj = 0; jj < 4; ++jj)
#pragma unroll
                for (int mt = 0; mt < 6; ++mt)
                    acc[jj][mt] = __builtin_amdgcn_mfma_f32_16x16x32_bf16(ah[mt], bh[jj], acc[jj][mt], 0, 0, 0);
#pragma unroll
            for (int jj = 0; jj < 4; ++jj)
#pragma unroll
                for (int mt = 0; mt < 6; ++mt)
                    acc[jj][mt] = __builtin_amdgcn_mfma_f32_16x16x32_bf16(al[mt], bh[jj], acc[jj][mt], 0, 0, 0);
#pragma unroll
            for (int jj = 0; jj < 4; ++jj)
#pragma unroll
                for (int mt = 0; mt < 6; ++mt)
                    acc[jj][mt] = __builtin_amdgcn_mfma_f32_16x16x32_bf16(ah[mt], bl[jj], acc[jj][mt], 0, 0, 0);
#pragma unroll
            for (int jj = 0; jj < 4; ++jj)
#pragma unroll
                for (int mt = 0; mt < 6; ++mt)
                    acc[jj][mt] = __builtin_amdgcn_mfma_f32_16x16x32_bf16(al[mt], bl[jj], acc[jj][mt], 0, 0, 0);
        }

        __syncthreads();   // all waves done reading state

        // tanh jet chain (lane-local) + write back both planes
#pragma unroll
        for (int jj = 0; jj < 4; ++jj) {
            const int j  = (wid * 4 + jj) * 16 + (lane & 15);
            const int kt = j >> 5, kg = (j >> 3) & 3, e = j & 7;
#pragma unroll
            for (int r = 0; r < 4; ++r) {
                const int p = (lane >> 4) * 4 + r;
                float z0 = acc[jj][0][r] + bias[jj];
                float z1 = acc[jj][1][r], z2 = acc[jj][2][r], z3 = acc[jj][3][r];
                float z4 = acc[jj][4][r], z5 = acc[jj][5][r];
                float a  = fast_tanh(z0);
                float td = 1.f - a * a;
                float m2 = -2.f * a * td;
                float o[6] = { a, td * z1, td * z2, td * z3,
                               fmaf(m2 * z1, z1, td * z4),
                               fmaf(m2 * z2, z2, td * z5) };
#pragma unroll
                for (int s = 0; s < 6; ++s) {
                    size_t off = (size_t)(s * 8 + kt) * 1024 + (size_t)(kg * 16 + p) * 16 + e * 2;
                    unsigned short h = f2bf(o[s]);
                    *(unsigned short*)(SH + off) = h;
                    *(unsigned short*)(SL + off) = f2bf(o[s] - bf2f(h));
                }
            }
        }
        __syncthreads();
    }

    // ---- output layer: residual_p = sum_j wout_j * (gt - s0 - s1) ----
    {
        const int p    = tid & 15;
        const int jseg = tid >> 4;
        float sum = 0.f;
#pragma unroll
        for (int jj = 0; jj < 16; ++jj) {
            const int j  = jseg * 16 + jj;
            const int kt = j >> 5, kg = (j >> 3) & 3, e = j & 7;
            float v[3];
#pragma unroll
            for (int s = 3; s < 6; ++s) {
                size_t off = (size_t)(s * 8 + kt) * 1024 + (size_t)(kg * 16 + p) * 16 + e * 2;
                v[s - 3] = bf2f(*(unsigned short*)(SH + off)) + bf2f(*(unsigned short*)(SL + off));
            }
            sum = fmaf(W_out[j], v[0] - v[1] - v[2], sum);
        }
        red[jseg * 16 + p] = sum;
    }
    __syncthreads();
    if (tid < PPW) {
        float s = 0.f;
        for (int g = 0; g < 16; ++g) s += red[g * 16 + tid];   // fixed order
        double d = (double)s;
        sq[tid] = d * d;
    }
    __syncthreads();
    if (tid == 0) {
        double tot = 0.0;
        for (int p = 0; p < PPW; ++p) tot += sq[p];            // fixed order
        partials[wg] = tot;
    }
}

__global__ void pinn_reduce_kernel(const double* __restrict__ partials, float* __restrict__ out)
{
    __shared__ double sh[256];
    double t = 0.0;
    for (int i = 0; i < NWG / 256; ++i) t += partials[threadIdx.x * (NWG / 256) + i]; // fixed order
    sh[threadIdx.x] = t;
    __syncthreads();
    for (int ofs = 128; ofs > 0; ofs >>= 1) {
        if ((int)threadIdx.x < ofs) sh[threadIdx.x] += sh[threadIdx.x + ofs];
        __syncthreads();
    }
    if (threadIdx.x == 0) {
        out[0] = (float)(sh[0] / (double)NPTS);  // pde_loss
        out[1] = 0.f;                            // ode_loss
    }
}

extern "C" void kernel_launch(void* const* d_in, const int* in_sizes, int n_in,
                              void* d_out, int out_size, void* d_ws, size_t ws_size,
                              hipStream_t stream)
{
    const float* X     = (const float*)d_in[0];
    const float* W_in  = (const float*)d_in[1];
    const float* b_in  = (const float*)d_in[2];
    const float* W_h   = (const float*)d_in[3];
    const float* b_h   = (const float*)d_in[4];
    const float* W_out = (const float*)d_in[5];
    // d_in[6] = b_out: constant output offset, zero derivative -> unused

    double*         partials = (double*)((char*)d_ws + WS_PARTIALS);
    unsigned short* whi      = (unsigned short*)((char*)d_ws + WS_WHI);
    unsigned short* wlo      = (unsigned short*)((char*)d_ws + WS_WLO);
    float*          out      = (float*)d_out;

    const size_t lds_bytes = 98304 + 256 + 1024 + 128;   // 99712
    (void)hipFuncSetAttribute((const void*)pinn_mfma,
                              hipFuncAttributeMaxDynamicSharedMemorySize, (int)lds_bytes);

    hipLaunchKernelGGL(prep_w, dim3(512), dim3(64), 0, stream, W_h, whi, wlo);
    hipLaunchKernelGGL(pinn_mfma, dim3(NWG), dim3(256), lds_bytes, stream,
                       X, W_in, b_in, b_h, W_out, whi, wlo, partials);
    hipLaunchKernelGGL(pinn_reduce_kernel, dim3(1), dim3(256), 0, stream,
                       partials, out);
}

// Round 3
// 1127.916 us; speedup vs baseline: 4.6762x; 1.3598x over previous
//
#include <hip/hip_runtime.h>
#include <hip/hip_bf16.h>

typedef __attribute__((ext_vector_type(8))) short  short8;
typedef __attribute__((ext_vector_type(4))) float  f32x4;

#define HIDDEN   256
#define NLAYERS  4
#define NPTS     131072
#define PPW      16
#define NWG      (NPTS / PPW)          // 8192

// workspace layout (bytes)
#define WS_PARTIALS   0                          // 8192 doubles = 64 KB
#define WS_WHI        65536
#define WPLANE_BYTES  (4 * 16 * 8 * 1024)        // 4 layers x 16 jt x 8 kt x 1KB = 512 KB
#define WS_WLO        (WS_WHI + WPLANE_BYTES)    // total ws use: 64KB + 1MB

__device__ __forceinline__ unsigned short f2bf(float f) {
    return __builtin_bit_cast(unsigned short, __float2bfloat16(f));   // HW RNE convert
}
__device__ __forceinline__ float bf2f(unsigned short h) {
    return __uint_as_float(((unsigned)h) << 16);
}
__device__ __forceinline__ float fast_tanh(float z) {
    float az = fabsf(z);
    float e  = __expf(2.f * az);                 // inf for big az -> r = 1, no NaN
    float r  = 1.f - __fdividef(2.f, e + 1.f);
    return copysignf(r, z);
}

// ---------------- weight prep: split W_h into bf16 hi/lo, fragment-contiguous ----------------
// B-fragment (layer, jt, kt): lane l holds W[k][j] for j = jt*16 + (l&15),
// k = kt*32 + (l>>4)*8 + e  (e = 0..7), stored at frag_base + l*8 ushorts.
__global__ void prep_w(const float* __restrict__ Wh,
                       unsigned short* __restrict__ whi, unsigned short* __restrict__ wlo)
{
    int b    = blockIdx.x;               // 512 = 4 layers x 16 jt x 8 kt
    int lay  = b >> 7;
    int jt   = (b >> 3) & 15;
    int kt   = b & 7;
    int lane = threadIdx.x;              // 64
    int j    = jt * 16 + (lane & 15);
    int k0   = kt * 32 + (lane >> 4) * 8;
    const float* W = Wh + (size_t)lay * HIDDEN * HIDDEN;
    size_t base = ((size_t)(lay * 16 + jt) * 8 + kt) * 512 + (size_t)lane * 8;  // ushort units
#pragma unroll
    for (int e = 0; e < 8; ++e) {
        float w = W[(size_t)(k0 + e) * HIDDEN + j];
        unsigned short h = f2bf(w);
        whi[base + e] = h;
        wlo[base + e] = f2bf(w - bf2f(h));
    }
}

// ---------------- fused PINN kernel (512 threads = 8 waves, 2 waves/SIMD) ----------------
// LDS state: 48 fragments per plane (mt = state 0..5, kt = 0..7), each 1 KB:
//   addr(plane, mt, kt, lane, e) = plane + (mt*8+kt)*1024 + lane*16 + e*2
// semantic: value(state s, point p, hidden j) at frag (s, j>>5),
//   lane = ((j>>3)&3)*16 + p, e = j&7.
__global__ __launch_bounds__(512, 1)
void pinn_mfma(const float* __restrict__ X,
               const float* __restrict__ W_in, const float* __restrict__ b_in,
               const float* __restrict__ b_h,  const float* __restrict__ W_out,
               const unsigned short* __restrict__ whi, const unsigned short* __restrict__ wlo,
               double* __restrict__ partials)
{
    extern __shared__ char lds[];
    char*   SH  = lds;                         // 48 KB  hi plane
    char*   SL  = lds + 48 * 1024;             // 48 KB  lo plane
    float*  xs  = (float*)(lds + 98304);       // 48 floats (pad to 256B)
    float*  red = (float*)(lds + 98304 + 256); // 512 floats
    double* sq  = (double*)(lds + 98304 + 256 + 2048); // 16 doubles

    const int tid  = threadIdx.x;
    const int lane = tid & 63;
    const int wid  = tid >> 6;                 // 0..7
    const int wg   = blockIdx.x;
    const int pt0  = wg * PPW;

    if (tid < 48) xs[tid] = X[(size_t)pt0 * 3 + tid];
    __syncthreads();

    // ---- input layer: thread pair owns hidden unit j = tid>>1; 8 points each ----
    {
        const int j  = tid >> 1;
        const int p0 = (tid & 1) * 8;
        const int kt = j >> 5, kg = (j >> 3) & 3, e = j & 7;
        float w0 = W_in[j], w1 = W_in[HIDDEN + j], w2 = W_in[2 * HIDDEN + j], bj = b_in[j];
#pragma unroll
        for (int pp = 0; pp < 8; ++pp) {
            const int p = p0 + pp;
            float x0 = xs[p * 3], x1 = xs[p * 3 + 1], x2 = xs[p * 3 + 2];
            float z  = fmaf(x0, w0, fmaf(x1, w1, fmaf(x2, w2, bj)));
            float a  = fast_tanh(z);
            float td = 1.f - a * a;
            float m2 = -2.f * a * td;
            float o[6] = { a, td * w0, td * w1, td * w2, m2 * w0 * w0, m2 * w1 * w1 };
#pragma unroll
            for (int s = 0; s < 6; ++s) {
                size_t off = (size_t)(s * 8 + kt) * 1024 + (size_t)(kg * 16 + p) * 16 + e * 2;
                unsigned short h = f2bf(o[s]);
                *(unsigned short*)(SH + off) = h;
                *(unsigned short*)(SL + off) = f2bf(o[s] - bf2f(h));
            }
        }
    }
    __syncthreads();

    // ---- hidden layers: split-bf16 MFMA GEMM, 3 products (ah*bh + al*bh + ah*bl) ----
#pragma unroll 1
    for (int l = 0; l < NLAYERS; ++l) {
        float bias[2];
#pragma unroll
        for (int jj = 0; jj < 2; ++jj)
            bias[jj] = b_h[l * HIDDEN + (wid * 2 + jj) * 16 + (lane & 15)];

        f32x4 acc[2][6];
#pragma unroll
        for (int jj = 0; jj < 2; ++jj)
#pragma unroll
            for (int mt = 0; mt < 6; ++mt)
                acc[jj][mt] = (f32x4){0.f, 0.f, 0.f, 0.f};

#pragma unroll 2
        for (int kt = 0; kt < 8; ++kt) {
            short8 ah[6], al[6];
#pragma unroll
            for (int mt = 0; mt < 6; ++mt) {
                size_t fo = (size_t)(mt * 8 + kt) * 1024 + (size_t)lane * 16;
                ah[mt] = *(const short8*)(SH + fo);
                al[mt] = *(const short8*)(SL + fo);
            }
            short8 bh[2], bl[2];
#pragma unroll
            for (int jj = 0; jj < 2; ++jj) {
                size_t fo = ((size_t)(l * 16 + wid * 2 + jj) * 8 + kt) * 512 + (size_t)lane * 8;
                bh[jj] = *(const short8*)(whi + fo);
                bl[jj] = *(const short8*)(wlo + fo);
            }
            // product-major for acc dependency distance (12 MFMA between reuses)
#pragma unroll
            for (int jj = 0; jj < 2; ++jj)
#pragma unroll
                for (int mt = 0; mt < 6; ++mt)
                    acc[jj][mt] = __builtin_amdgcn_mfma_f32_16x16x32_bf16(ah[mt], bh[jj], acc[jj][mt], 0, 0, 0);
#pragma unroll
            for (int jj = 0; jj < 2; ++jj)
#pragma unroll
                for (int mt = 0; mt < 6; ++mt)
                    acc[jj][mt] = __builtin_amdgcn_mfma_f32_16x16x32_bf16(al[mt], bh[jj], acc[jj][mt], 0, 0, 0);
#pragma unroll
            for (int jj = 0; jj < 2; ++jj)
#pragma unroll
                for (int mt = 0; mt < 6; ++mt)
                    acc[jj][mt] = __builtin_amdgcn_mfma_f32_16x16x32_bf16(ah[mt], bl[jj], acc[jj][mt], 0, 0, 0);
        }

        __syncthreads();   // all waves done reading state

        // tanh jet chain (lane-local) + write back both planes
#pragma unroll
        for (int jj = 0; jj < 2; ++jj) {
            const int j  = (wid * 2 + jj) * 16 + (lane & 15);
            const int kt = j >> 5, kg = (j >> 3) & 3, e = j & 7;
#pragma unroll
            for (int r = 0; r < 4; ++r) {
                const int p = (lane >> 4) * 4 + r;
                float z0 = acc[jj][0][r] + bias[jj];
                float z1 = acc[jj][1][r], z2 = acc[jj][2][r], z3 = acc[jj][3][r];
                float z4 = acc[jj][4][r], z5 = acc[jj][5][r];
                float a  = fast_tanh(z0);
                float td = 1.f - a * a;
                float m2 = -2.f * a * td;
                float o[6] = { a, td * z1, td * z2, td * z3,
                               fmaf(m2 * z1, z1, td * z4),
                               fmaf(m2 * z2, z2, td * z5) };
#pragma unroll
                for (int s = 0; s < 6; ++s) {
                    size_t off = (size_t)(s * 8 + kt) * 1024 + (size_t)(kg * 16 + p) * 16 + e * 2;
                    unsigned short h = f2bf(o[s]);
                    *(unsigned short*)(SH + off) = h;
                    *(unsigned short*)(SL + off) = f2bf(o[s] - bf2f(h));
                }
            }
        }
        __syncthreads();
    }

    // ---- output layer: residual_p = sum_j wout_j * (gt - s0 - s1) ----
    {
        const int p   = tid & 15;
        const int seg = tid >> 4;          // 0..31, 8 j's each
        float sum = 0.f;
#pragma unroll
        for (int jj = 0; jj < 8; ++jj) {
            const int j  = seg * 8 + jj;
            const int kt = j >> 5, kg = (j >> 3) & 3, e = j & 7;
            float v[3];
#pragma unroll
            for (int s = 3; s < 6; ++s) {
                size_t off = (size_t)(s * 8 + kt) * 1024 + (size_t)(kg * 16 + p) * 16 + e * 2;
                v[s - 3] = bf2f(*(unsigned short*)(SH + off)) + bf2f(*(unsigned short*)(SL + off));
            }
            sum = fmaf(W_out[j], v[0] - v[1] - v[2], sum);
        }
        red[seg * 16 + p] = sum;
    }
    __syncthreads();
    if (tid < PPW) {
        float s = 0.f;
        for (int g = 0; g < 32; ++g) s += red[g * 16 + tid];   // fixed order
        double d = (double)s;
        sq[tid] = d * d;
    }
    __syncthreads();
    if (tid == 0) {
        double tot = 0.0;
        for (int p = 0; p < PPW; ++p) tot += sq[p];            // fixed order
        partials[wg] = tot;
    }
}

__global__ void pinn_reduce_kernel(const double* __restrict__ partials, float* __restrict__ out)
{
    __shared__ double sh[256];
    double t = 0.0;
    for (int i = 0; i < NWG / 256; ++i) t += partials[threadIdx.x * (NWG / 256) + i]; // fixed order
    sh[threadIdx.x] = t;
    __syncthreads();
    for (int ofs = 128; ofs > 0; ofs >>= 1) {
        if ((int)threadIdx.x < ofs) sh[threadIdx.x] += sh[threadIdx.x + ofs];
        __syncthreads();
    }
    if (threadIdx.x == 0) {
        out[0] = (float)(sh[0] / (double)NPTS);  // pde_loss
        out[1] = 0.f;                            // ode_loss
    }
}

extern "C" void kernel_launch(void* const* d_in, const int* in_sizes, int n_in,
                              void* d_out, int out_size, void* d_ws, size_t ws_size,
                              hipStream_t stream)
{
    const float* X     = (const float*)d_in[0];
    const float* W_in  = (const float*)d_in[1];
    const float* b_in  = (const float*)d_in[2];
    const float* W_h   = (const float*)d_in[3];
    const float* b_h   = (const float*)d_in[4];
    const float* W_out = (const float*)d_in[5];
    // d_in[6] = b_out: constant output offset, zero derivative -> unused

    double*         partials = (double*)((char*)d_ws + WS_PARTIALS);
    unsigned short* whi      = (unsigned short*)((char*)d_ws + WS_WHI);
    unsigned short* wlo      = (unsigned short*)((char*)d_ws + WS_WLO);
    float*          out      = (float*)d_out;

    const size_t lds_bytes = 98304 + 256 + 2048 + 128;   // 100736
    (void)hipFuncSetAttribute((const void*)pinn_mfma,
                              hipFuncAttributeMaxDynamicSharedMemorySize, (int)lds_bytes);

    hipLaunchKernelGGL(prep_w, dim3(512), dim3(64), 0, stream, W_h, whi, wlo);
    hipLaunchKernelGGL(pinn_mfma, dim3(NWG), dim3(512), lds_bytes, stream,
                       X, W_in, b_in, b_h, W_out, whi, wlo, partials);
    hipLaunchKernelGGL(pinn_reduce_kernel, dim3(1), dim3(256), 0, stream,
                       partials, out);
}

// Round 4
// 810.553 us; speedup vs baseline: 6.5071x; 1.3915x over previous
//
#include <hip/hip_runtime.h>
#include <hip/hip_bf16.h>

typedef __attribute__((ext_vector_type(8))) short  short8;
typedef __attribute__((ext_vector_type(4))) float  f32x4;

#define HIDDEN   256
#define NLAYERS  4
#define NPTS     131072
#define PPW      16
#define NWG      (NPTS / PPW)          // 8192
#define NSTATE   5                     // h, g0, g1, gt, S=s0+s1

// workspace layout (bytes)
#define WS_PARTIALS   0                          // 8192 doubles = 64 KB
#define WS_WHI        65536
#define WPLANE_BYTES  (4 * 16 * 8 * 1024)        // 4 layers x 16 jt x 8 kt x 1KB = 512 KB
#define WS_WLO        (WS_WHI + WPLANE_BYTES)    // total ws use: 64KB + 1MB

__device__ __forceinline__ unsigned short f2bf(float f) {
    return __builtin_bit_cast(unsigned short, __float2bfloat16(f));   // HW RNE convert
}
__device__ __forceinline__ float bf2f(unsigned short h) {
    return __uint_as_float(((unsigned)h) << 16);
}
__device__ __forceinline__ float fast_tanh(float z) {
    float az = fabsf(z);
    float e  = __expf(2.f * az);                 // inf for big az -> r = 1, no NaN
    float r  = 1.f - __fdividef(2.f, e + 1.f);
    return copysignf(r, z);
}

// ---------------- weight prep: split W_h into bf16 hi/lo, fragment-contiguous ----------------
// B-fragment (layer, jt, kt): lane l holds W[k][j] for j = jt*16 + (l&15),
// k = kt*32 + (l>>4)*8 + e  (e = 0..7), stored at frag_base + l*8 ushorts.
__global__ void prep_w(const float* __restrict__ Wh,
                       unsigned short* __restrict__ whi, unsigned short* __restrict__ wlo)
{
    int b    = blockIdx.x;               // 512 = 4 layers x 16 jt x 8 kt
    int lay  = b >> 7;
    int jt   = (b >> 3) & 15;
    int kt   = b & 7;
    int lane = threadIdx.x;              // 64
    int j    = jt * 16 + (lane & 15);
    int k0   = kt * 32 + (lane >> 4) * 8;
    const float* W = Wh + (size_t)lay * HIDDEN * HIDDEN;
    size_t base = ((size_t)(lay * 16 + jt) * 8 + kt) * 512 + (size_t)lane * 8;  // ushort units
#pragma unroll
    for (int e = 0; e < 8; ++e) {
        float w = W[(size_t)(k0 + e) * HIDDEN + j];
        unsigned short h = f2bf(w);
        whi[base + e] = h;
        wlo[base + e] = f2bf(w - bf2f(h));
    }
}

// ---------------- fused PINN kernel: 512 thr (8 waves), 80 KB LDS -> 2 WGs/CU ----------------
// LDS state: NSTATE*8 fragments per plane (mt = state 0..4, kt = 0..7), each 1 KB:
//   addr(plane, mt, kt, lane, e) = plane + (mt*8+kt)*1024 + lane*16 + e*2
// semantic: value(state s, point p, hidden j) at frag (s, j>>5),
//   lane = ((j>>3)&3)*16 + p, e = j&7.
// red/sq alias the h-plane (s=0), which is dead during the output phase.
__global__ __launch_bounds__(512, 4)
void pinn_mfma(const float* __restrict__ X,
               const float* __restrict__ W_in, const float* __restrict__ b_in,
               const float* __restrict__ b_h,  const float* __restrict__ W_out,
               const unsigned short* __restrict__ whi, const unsigned short* __restrict__ wlo,
               double* __restrict__ partials)
{
    extern __shared__ char lds[];
    char*   SH  = lds;                           // 40960 B  hi plane (5 states)
    char*   SL  = lds + NSTATE * 8 * 1024;       // 40960 B  lo plane
    float*  red = (float*)lds;                   // aliases h-plane: 512 floats
    double* sq  = (double*)(lds + 2048);         // aliases h-plane: 16 doubles

    const int tid  = threadIdx.x;
    const int lane = tid & 63;
    const int wid  = tid >> 6;                   // 0..7
    const int wg   = blockIdx.x;
    const int pt0  = wg * PPW;

    // ---- input layer: thread pair owns hidden unit j = tid>>1; 8 points each ----
    {
        const int j  = tid >> 1;
        const int p0 = (tid & 1) * 8;
        const int kt = j >> 5, kg = (j >> 3) & 3, e = j & 7;
        float w0 = W_in[j], w1 = W_in[HIDDEN + j], w2 = W_in[2 * HIDDEN + j], bj = b_in[j];
        float sw = fmaf(w0, w0, w1 * w1);        // w0^2 + w1^2
#pragma unroll
        for (int pp = 0; pp < 8; ++pp) {
            const int p = p0 + pp;
            const float* xp = X + (size_t)(pt0 + p) * 3;
            float z  = fmaf(xp[0], w0, fmaf(xp[1], w1, fmaf(xp[2], w2, bj)));
            float a  = fast_tanh(z);
            float td = 1.f - a * a;
            float m2 = -2.f * a * td;
            float o[NSTATE] = { a, td * w0, td * w1, td * w2, m2 * sw };
#pragma unroll
            for (int s = 0; s < NSTATE; ++s) {
                size_t off = (size_t)(s * 8 + kt) * 1024 + (size_t)(kg * 16 + p) * 16 + e * 2;
                unsigned short h = f2bf(o[s]);
                *(unsigned short*)(SH + off) = h;
                *(unsigned short*)(SL + off) = f2bf(o[s] - bf2f(h));
            }
        }
    }
    __syncthreads();

    // ---- hidden layers: split-bf16 MFMA GEMM, 3 products (ah*bh + al*bh + ah*bl) ----
#pragma unroll 1
    for (int l = 0; l < NLAYERS; ++l) {
        float bias[2];
#pragma unroll
        for (int jj = 0; jj < 2; ++jj)
            bias[jj] = b_h[l * HIDDEN + (wid * 2 + jj) * 16 + (lane & 15)];

        f32x4 acc[2][NSTATE];
#pragma unroll
        for (int jj = 0; jj < 2; ++jj)
#pragma unroll
            for (int mt = 0; mt < NSTATE; ++mt)
                acc[jj][mt] = (f32x4){0.f, 0.f, 0.f, 0.f};

#pragma unroll 2
        for (int kt = 0; kt < 8; ++kt) {
            short8 ah[NSTATE], al[NSTATE];
#pragma unroll
            for (int mt = 0; mt < NSTATE; ++mt) {
                size_t fo = (size_t)(mt * 8 + kt) * 1024 + (size_t)lane * 16;
                ah[mt] = *(const short8*)(SH + fo);
                al[mt] = *(const short8*)(SL + fo);
            }
            short8 bh[2], bl[2];
#pragma unroll
            for (int jj = 0; jj < 2; ++jj) {
                size_t fo = ((size_t)(l * 16 + wid * 2 + jj) * 8 + kt) * 512 + (size_t)lane * 8;
                bh[jj] = *(const short8*)(whi + fo);
                bl[jj] = *(const short8*)(wlo + fo);
            }
            // product-major: 10 MFMAs between accumulator reuses
#pragma unroll
            for (int jj = 0; jj < 2; ++jj)
#pragma unroll
                for (int mt = 0; mt < NSTATE; ++mt)
                    acc[jj][mt] = __builtin_amdgcn_mfma_f32_16x16x32_bf16(ah[mt], bh[jj], acc[jj][mt], 0, 0, 0);
#pragma unroll
            for (int jj = 0; jj < 2; ++jj)
#pragma unroll
                for (int mt = 0; mt < NSTATE; ++mt)
                    acc[jj][mt] = __builtin_amdgcn_mfma_f32_16x16x32_bf16(al[mt], bh[jj], acc[jj][mt], 0, 0, 0);
#pragma unroll
            for (int jj = 0; jj < 2; ++jj)
#pragma unroll
                for (int mt = 0; mt < NSTATE; ++mt)
                    acc[jj][mt] = __builtin_amdgcn_mfma_f32_16x16x32_bf16(ah[mt], bl[jj], acc[jj][mt], 0, 0, 0);
        }

        __syncthreads();   // all waves done reading state

        // tanh jet chain (lane-local) + write back both planes
#pragma unroll
        for (int jj = 0; jj < 2; ++jj) {
            const int j  = (wid * 2 + jj) * 16 + (lane & 15);
            const int kt = j >> 5, kg = (j >> 3) & 3, e = j & 7;
#pragma unroll
            for (int r = 0; r < 4; ++r) {
                const int p = (lane >> 4) * 4 + r;
                float z0 = acc[jj][0][r] + bias[jj];
                float z1 = acc[jj][1][r], z2 = acc[jj][2][r], z3 = acc[jj][3][r];
                float zS = acc[jj][4][r];
                float a  = fast_tanh(z0);
                float td = 1.f - a * a;
                float m2 = -2.f * a * td;
                float o[NSTATE] = { a, td * z1, td * z2, td * z3,
                                    fmaf(td, zS, m2 * fmaf(z1, z1, z2 * z2)) };
#pragma unroll
                for (int s = 0; s < NSTATE; ++s) {
                    size_t off = (size_t)(s * 8 + kt) * 1024 + (size_t)(kg * 16 + p) * 16 + e * 2;
                    unsigned short h = f2bf(o[s]);
                    *(unsigned short*)(SH + off) = h;
                    *(unsigned short*)(SL + off) = f2bf(o[s] - bf2f(h));
                }
            }
        }
        __syncthreads();
    }

    // ---- output layer: residual_p = sum_j wout_j * (gt - S) ----
    {
        const int p   = tid & 15;
        const int seg = tid >> 4;          // 0..31, 8 j's each
        float sum = 0.f;
#pragma unroll
        for (int jj = 0; jj < 8; ++jj) {
            const int j  = seg * 8 + jj;
            const int kt = j >> 5, kg = (j >> 3) & 3, e = j & 7;
            size_t off3 = (size_t)(3 * 8 + kt) * 1024 + (size_t)(kg * 16 + p) * 16 + e * 2;
            size_t off4 = (size_t)(4 * 8 + kt) * 1024 + (size_t)(kg * 16 + p) * 16 + e * 2;
            float gt = bf2f(*(unsigned short*)(SH + off3)) + bf2f(*(unsigned short*)(SL + off3));
            float S  = bf2f(*(unsigned short*)(SH + off4)) + bf2f(*(unsigned short*)(SL + off4));
            sum = fmaf(W_out[j], gt - S, sum);
        }
        red[seg * 16 + p] = sum;           // writes h-plane region (s=0) only
    }
    __syncthreads();
    if (tid < PPW) {
        float s = 0.f;
        for (int g = 0; g < 32; ++g) s += red[g * 16 + tid];   // fixed order
        double d = (double)s;
        sq[tid] = d * d;
    }
    __syncthreads();
    if (tid == 0) {
        double tot = 0.0;
        for (int p = 0; p < PPW; ++p) tot += sq[p];            // fixed order
        partials[wg] = tot;
    }
}

__global__ void pinn_reduce_kernel(const double* __restrict__ partials, float* __restrict__ out)
{
    __shared__ double sh[256];
    double t = 0.0;
    for (int i = 0; i < NWG / 256; ++i) t += partials[threadIdx.x * (NWG / 256) + i]; // fixed order
    sh[threadIdx.x] = t;
    __syncthreads();
    for (int ofs = 128; ofs > 0; ofs >>= 1) {
        if ((int)threadIdx.x < ofs) sh[threadIdx.x] += sh[threadIdx.x + ofs];
        __syncthreads();
    }
    if (threadIdx.x == 0) {
        out[0] = (float)(sh[0] / (double)NPTS);  // pde_loss
        out[1] = 0.f;                            // ode_loss
    }
}

extern "C" void kernel_launch(void* const* d_in, const int* in_sizes, int n_in,
                              void* d_out, int out_size, void* d_ws, size_t ws_size,
                              hipStream_t stream)
{
    const float* X     = (const float*)d_in[0];
    const float* W_in  = (const float*)d_in[1];
    const float* b_in  = (const float*)d_in[2];
    const float* W_h   = (const float*)d_in[3];
    const float* b_h   = (const float*)d_in[4];
    const float* W_out = (const float*)d_in[5];
    // d_in[6] = b_out: constant output offset, zero derivative -> unused

    double*         partials = (double*)((char*)d_ws + WS_PARTIALS);
    unsigned short* whi      = (unsigned short*)((char*)d_ws + WS_WHI);
    unsigned short* wlo      = (unsigned short*)((char*)d_ws + WS_WLO);
    float*          out      = (float*)d_out;

    const size_t lds_bytes = (size_t)NSTATE * 8 * 1024 * 2;   // 81920 B -> 2 WGs/CU
    (void)hipFuncSetAttribute((const void*)pinn_mfma,
                              hipFuncAttributeMaxDynamicSharedMemorySize, (int)lds_bytes);

    hipLaunchKernelGGL(prep_w, dim3(512), dim3(64), 0, stream, W_h, whi, wlo);
    hipLaunchKernelGGL(pinn_mfma, dim3(NWG), dim3(512), lds_bytes, stream,
                       X, W_in, b_in, b_h, W_out, whi, wlo, partials);
    hipLaunchKernelGGL(pinn_reduce_kernel, dim3(1), dim3(256), 0, stream,
                       partials, out);
}